// Round 4
// baseline (8327.161 us; speedup 1.0000x reference)
//
#include <hip/hip_runtime.h>
#include <cstdint>
#include <cstddef>

#define BATCH 16384

typedef float f32x4 __attribute__((ext_vector_type(4)));
typedef _Float16 f16x8 __attribute__((ext_vector_type(8)));

__device__ __forceinline__ unsigned short f2h_bits(float f) {
  _Float16 h = (_Float16)f;
  return __builtin_bit_cast(unsigned short, h);
}

__device__ __forceinline__ void async_cp16(const void* g, void* l) {
  __builtin_amdgcn_global_load_lds(
      (const __attribute__((address_space(1))) unsigned int*)g,
      (__attribute__((address_space(3))) unsigned int*)l, 16, 0, 0);
}

// Barrier WITHOUT the full vmcnt(0) drain __syncthreads would force.
#define PIPE_BAR_3() asm volatile("s_waitcnt vmcnt(3)\n\ts_barrier" ::: "memory")
#define PIPE_BAR_2() asm volatile("s_waitcnt vmcnt(2)\n\ts_barrier" ::: "memory")
#define PIPE_BAR_0() asm volatile("s_waitcnt vmcnt(0)\n\ts_barrier" ::: "memory")

// ---------------------------------------------------------------------------
// Champion hidden-layer GEMM (R6 structure): 256x128 tile, 8 waves 4x2,
// wave tile 64x64, BK=32, 3-stage LDS pipe, vmcnt(3) counted boundary.
// Used for layer 0 (K=64) unchanged.
// ---------------------------------------------------------------------------
template <int BM, int BN, int RT, int CT, int K, int N, bool RELU>
__launch_bounds__(512, 4)
__global__ void gemm_h(const unsigned short* __restrict__ A,
                       const unsigned short* __restrict__ Bw,
                       const float* __restrict__ Wfull,
                       const float* __restrict__ bias,
                       float tval,
                       unsigned short* __restrict__ Ch) {
  constexpr int BK = 32;
  constexpr int NI = K / BK;
  static_assert(NI >= 2, "pipeline needs >=2 stages");
  static_assert((BM * 4 + BN * 4) / 512 == 3, "vmcnt(3) assumes 3 loads/stage");
  static_assert(BM == 4 * RT * 16 && BN == 2 * CT * 16, "4x2 waves");
  __shared__ __align__(16) unsigned short smA[3][BM * BK];
  __shared__ __align__(16) unsigned short smB[3][BN * BK];
  __shared__ float biasLds[BN];

  const int tid = threadIdx.x;
  const int wave = tid >> 6;
  const int lane = tid & 63;
  const int quad = lane >> 4;
  const int r16 = lane & 15;

  const int rowA0 = blockIdx.x * BM;
  const int rowB0 = blockIdx.y * BN;
  const int waveM = wave >> 1;
  const int waveN = wave & 1;

  if (tid < BN) {
    const int col = rowB0 + tid;
    biasLds[tid] = bias[col] + tval * Wfull[(size_t)col * (K + 1) + K];
  }

  auto stage = [&](int k0, int buf) {
#pragma unroll
    for (int i = 0; i < BM * 4 / 512; ++i) {
      const int s = i * 512 + tid;
      const int row = s >> 2;
      const int c = (s & 3) ^ ((row >> 1) & 3);
      const unsigned short* g = A + (size_t)(rowA0 + row) * K + (k0 + c * 8);
      char* l = ((char*)smA[buf]) + (size_t)(i * 512 + (wave << 6)) * 16;
      async_cp16(g, l);
    }
    {
      const int s = tid;
      const int row = s >> 2;
      const int c = (s & 3) ^ ((row >> 1) & 3);
      const unsigned short* g = Bw + (size_t)(rowB0 + row) * K + (k0 + c * 8);
      char* l = ((char*)smB[buf]) + (size_t)((wave << 6)) * 16;
      async_cp16(g, l);
    }
  };

  f32x4 acc[RT][CT];
  const f32x4 zero = {0.f, 0.f, 0.f, 0.f};
#pragma unroll
  for (int i = 0; i < RT; ++i)
#pragma unroll
    for (int j = 0; j < CT; ++j) acc[i][j] = zero;

  auto compute = [&](int buf) {
    const unsigned short* sA = smA[buf];
    const unsigned short* sB = smB[buf];
    f16x8 af[RT], bfr[CT];
#pragma unroll
    for (int nt = 0; nt < CT; ++nt) {
      const int row = waveN * (CT * 16) + nt * 16 + r16;
      const int cp = quad ^ ((row >> 1) & 3);
      bfr[nt] = *(const f16x8*)(sB + row * BK + cp * 8);
    }
#pragma unroll
    for (int mt = 0; mt < RT; ++mt) {
      const int row = waveM * (RT * 16) + mt * 16 + r16;
      const int cp = quad ^ ((row >> 1) & 3);
      af[mt] = *(const f16x8*)(sA + row * BK + cp * 8);
    }
#pragma unroll
    for (int mt = 0; mt < RT; ++mt)
#pragma unroll
      for (int nt = 0; nt < CT; ++nt)
        acc[mt][nt] =
            __builtin_amdgcn_mfma_f32_16x16x32_f16(af[mt], bfr[nt], acc[mt][nt], 0, 0, 0);
  };

  stage(0, 0);
  stage(BK, 1);

#pragma unroll
  for (int kk = 0; kk < NI - 1; ++kk) {
    PIPE_BAR_3();
    if (kk + 2 < NI) stage((kk + 2) * BK, (kk + 2) % 3);
    compute(kk % 3);
  }
  PIPE_BAR_0();
  compute((NI - 1) % 3);

#pragma unroll
  for (int mt = 0; mt < RT; ++mt) {
    const int grow0 = rowA0 + waveM * (RT * 16) + mt * 16 + quad * 4;
#pragma unroll
    for (int nt = 0; nt < CT; ++nt) {
      const int lcol = waveN * (CT * 16) + nt * 16 + r16;
      const int gcol = rowB0 + lcol;
      const float bi = biasLds[lcol];
#pragma unroll
      for (int r = 0; r < 4; ++r) {
        float v = acc[mt][nt][r] + bi;
        if (RELU) v = fmaxf(v, 0.0f);
        Ch[(size_t)(grow0 + r) * N + gcol] = f2h_bits(v);
      }
    }
  }
}

// ---------------------------------------------------------------------------
// Big-layer GEMM: champion structure, but B-FRAGMENTS READ FROM GLOBAL
// (L2/L1-cached; B panel = 256 KB/block, 4 waves share each col-half via L1).
// Removes smB entirely: halves LDS read traffic (the structural limiter:
// window model was LDS 1890 cy vs MFMA 1024 cy) and halves staging loads.
// A-only 3-stage pipe -> 2 loads/stage -> boundary vmcnt(2).
// Per-iter order is PINNED with sched_barrier(0):
//   [bar vmcnt(2)] -> B-frag global loads (4) -> stage A(k+2) (2) -> compute.
// Queue at compute: [A(k+1)x2, Bx4, A(k+2)x2]; compiler's data-dep waits for
// bfr[0..3] are vmcnt(5..2) -> drains A(k+1) (issued 1 iter ago, already
// landed) and B, NEVER the fresh A(k+2) prefetch. Boundary vmcnt(2) then
// holds A(k+2) in flight across the barrier. Verified for tail iters too
// (kk=NI-2: no stage -> bfr[3] forces vmcnt(0), all old, free).
// ---------------------------------------------------------------------------
template <int BM, int BN, int RT, int CT, int K, int N, bool RELU>
__launch_bounds__(512, 4)
__global__ void gemm_hb(const unsigned short* __restrict__ A,
                        const unsigned short* __restrict__ Bw,
                        const float* __restrict__ Wfull,
                        const float* __restrict__ bias,
                        float tval,
                        unsigned short* __restrict__ Ch) {
  constexpr int BK = 32;
  constexpr int NI = K / BK;
  static_assert(NI >= 2, "pipeline needs >=2 stages");
  static_assert(BM * 4 / 512 == 2, "A stage = 2 loads/thread");
  static_assert(BM == 4 * RT * 16 && BN == 2 * CT * 16, "4x2 waves");
  __shared__ __align__(16) unsigned short smA[3][BM * BK];
  __shared__ float biasLds[BN];

  const int tid = threadIdx.x;
  const int wave = tid >> 6;
  const int lane = tid & 63;
  const int quad = lane >> 4;
  const int r16 = lane & 15;

  const int rowA0 = blockIdx.x * BM;
  const int rowB0 = blockIdx.y * BN;
  const int waveM = wave >> 1;
  const int waveN = wave & 1;

  if (tid < BN) {
    const int col = rowB0 + tid;
    biasLds[tid] = bias[col] + tval * Wfull[(size_t)col * (K + 1) + K];
  }

  // A staging: 256x32 fp16 = 1024 chunks, 2/thread; XOR swizzle on source
  // chunk so frag ds_read_b128 is conflict-free (same as champion).
  auto stage = [&](int k0, int buf) {
#pragma unroll
    for (int i = 0; i < 2; ++i) {
      const int s = i * 512 + tid;
      const int row = s >> 2;
      const int c = (s & 3) ^ ((row >> 1) & 3);
      const unsigned short* g = A + (size_t)(rowA0 + row) * K + (k0 + c * 8);
      char* l = ((char*)smA[buf]) + (size_t)(i * 512 + (wave << 6)) * 16;
      async_cp16(g, l);
    }
  };

  f32x4 acc[RT][CT];
  const f32x4 zero = {0.f, 0.f, 0.f, 0.f};
#pragma unroll
  for (int i = 0; i < RT; ++i)
#pragma unroll
    for (int j = 0; j < CT; ++j) acc[i][j] = zero;

  stage(0, 0);
  stage(BK, 1);

#pragma unroll
  for (int kk = 0; kk < NI; ++kk) {
    PIPE_BAR_2();  // stage kk done; stage kk+1 (2 loads) stays in flight

    // B fragments straight from global (L2/L1-hot weight panel).
    f16x8 bfr[CT];
#pragma unroll
    for (int nt = 0; nt < CT; ++nt) {
      const int row = rowB0 + waveN * (CT * 16) + nt * 16 + r16;
      bfr[nt] = *(const f16x8*)(Bw + (size_t)row * K + kk * BK + quad * 8);
    }
    __builtin_amdgcn_sched_barrier(0);  // B loads issue BEFORE A prefetch

    if (kk + 2 < NI) stage((kk + 2) * BK, (kk + 2) % 3);
    __builtin_amdgcn_sched_barrier(0);  // A prefetch issues BEFORE compute

    const unsigned short* sA = smA[kk % 3];
    f16x8 af[RT];
#pragma unroll
    for (int mt = 0; mt < RT; ++mt) {
      const int row = waveM * (RT * 16) + mt * 16 + r16;
      const int cp = quad ^ ((row >> 1) & 3);
      af[mt] = *(const f16x8*)(sA + row * BK + cp * 8);
    }
#pragma unroll
    for (int mt = 0; mt < RT; ++mt)
#pragma unroll
      for (int nt = 0; nt < CT; ++nt)
        acc[mt][nt] =
            __builtin_amdgcn_mfma_f32_16x16x32_f16(af[mt], bfr[nt], acc[mt][nt], 0, 0, 0);
  }

  // epilogue: C/D layout col=lane&15, row=(lane>>4)*4+r
#pragma unroll
  for (int mt = 0; mt < RT; ++mt) {
    const int grow0 = rowA0 + waveM * (RT * 16) + mt * 16 + quad * 4;
#pragma unroll
    for (int nt = 0; nt < CT; ++nt) {
      const int lcol = waveN * (CT * 16) + nt * 16 + r16;
      const int gcol = rowB0 + lcol;
      const float bi = biasLds[lcol];
#pragma unroll
      for (int r = 0; r < 4; ++r) {
        float v = acc[mt][nt][r] + bi;
        if (RELU) v = fmaxf(v, 0.0f);
        Ch[(size_t)(grow0 + r) * N + gcol] = f2h_bits(v);
      }
    }
  }
}

// ---------------------------------------------------------------------------
// Last layer fused with RK4 combine (BM=32, BN=64 full width), dbuf BK=32.
// ---------------------------------------------------------------------------
__launch_bounds__(256, 4)
__global__ void gemm_l4(const unsigned short* __restrict__ A,
                        const unsigned short* __restrict__ Bw,
                        const float* __restrict__ Wfull,
                        const float* __restrict__ bias,
                        float tval,
                        float* __restrict__ y, float* __restrict__ ksum,
                        unsigned short* __restrict__ yh,
                        float* __restrict__ outp, int mode, float dt) {
  constexpr int K = 1024, BK = 32, BM = 32, BN = 64, NI = K / BK;
  __shared__ __align__(16) unsigned short smA[2][BM * BK];
  __shared__ __align__(16) unsigned short smB[2][BN * BK];
  __shared__ float biasLds[BN];

  const int tid = threadIdx.x;
  const int wave = tid >> 6;
  const int lane = tid & 63;
  const int quad = lane >> 4;
  const int r16 = lane & 15;

  const int rowA0 = blockIdx.x * BM;
  const int waveM = wave >> 1;
  const int waveN = wave & 1;

  if (tid < BN) {
    biasLds[tid] = bias[tid] + tval * Wfull[(size_t)tid * (K + 1) + K];
  }

  auto stage = [&](int k0, int buf) {
    if (tid < BM * 4) {
      const int s = tid;
      const int row = s >> 2;
      const int c = (s & 3) ^ ((row >> 1) & 3);
      const unsigned short* g = A + (size_t)(rowA0 + row) * K + (k0 + c * 8);
      char* l = ((char*)smA[buf]) + (size_t)(wave << 6) * 16;
      async_cp16(g, l);
    }
    {
      const int s = tid;
      const int row = s >> 2;
      const int c = (s & 3) ^ ((row >> 1) & 3);
      const unsigned short* g = Bw + (size_t)row * K + (k0 + c * 8);
      char* l = ((char*)smB[buf]) + (size_t)(wave << 6) * 16;
      async_cp16(g, l);
    }
  };

  f32x4 acc[2];
  const f32x4 zero = {0.f, 0.f, 0.f, 0.f};
  acc[0] = zero; acc[1] = zero;

  stage(0, 0);

#pragma unroll 2
  for (int kk = 0; kk < NI; ++kk) {
    __syncthreads();
    if (kk + 1 < NI) stage((kk + 1) * BK, (kk + 1) & 1);

    const unsigned short* sA = smA[kk & 1];
    const unsigned short* sB = smB[kk & 1];
    f16x8 af, bfr[2];
    {
      const int row = waveM * 16 + r16;
      const int cp = quad ^ ((row >> 1) & 3);
      af = *(const f16x8*)(sA + row * BK + cp * 8);
    }
#pragma unroll
    for (int nt = 0; nt < 2; ++nt) {
      const int row = (waveN * 2 + nt) * 16 + r16;
      const int cp = quad ^ ((row >> 1) & 3);
      bfr[nt] = *(const f16x8*)(sB + row * BK + cp * 8);
    }
#pragma unroll
    for (int nt = 0; nt < 2; ++nt)
      acc[nt] = __builtin_amdgcn_mfma_f32_16x16x32_f16(af, bfr[nt], acc[nt], 0, 0, 0);
  }

  const int grow0 = rowA0 + waveM * 16 + quad * 4;
#pragma unroll
  for (int nt = 0; nt < 2; ++nt) {
    const int col = waveN * 32 + nt * 16 + r16;
    const float bi = biasLds[col];
#pragma unroll
    for (int r = 0; r < 4; ++r) {
      const float k = acc[nt][r] + bi;
      const int row = grow0 + r;
      const int idx = row * 64 + col;
      if (mode == 0) {
        ksum[idx] = k;
        yh[idx] = f2h_bits(y[idx] + 0.5f * dt * k);
      } else if (mode == 1) {
        ksum[idx] += 2.f * k;
        yh[idx] = f2h_bits(y[idx] + 0.5f * dt * k);
      } else if (mode == 2) {
        ksum[idx] += 2.f * k;
        yh[idx] = f2h_bits(y[idx] + dt * k);
      } else {
        const float yn = y[idx] + (dt / 6.f) * (ksum[idx] + k);
        y[idx] = yn;
        yh[idx] = f2h_bits(yn);
        if (outp && col < 32) outp[row * 32 + col] = yn;
      }
    }
  }
}

// fp32 W (N x (K+1), time col dropped) -> fp16 Wh (N x K), row-major
__global__ void conv_w(const float* __restrict__ W, unsigned short* __restrict__ Wh,
                       int N, int K) {
  const int idx = blockIdx.x * 256 + threadIdx.x;
  if (idx < N * K) {
    const int n = idx / K;
    const int k = idx - n * K;
    Wh[idx] = f2h_bits(W[(size_t)n * (K + 1) + k]);
  }
}

// y0 = concat(x, aug); row-major fp32 + fp16 copy
__global__ void init_y(const float* __restrict__ x, const float* __restrict__ aug,
                       float* __restrict__ y, unsigned short* __restrict__ yh) {
  const int idx = blockIdx.x * 256 + threadIdx.x;  // BATCH*64
  const int i = idx >> 6;
  const int j = idx & 63;
  const float v = (j < 32) ? x[i * 32 + j] : aug[i * 32 + (j - 32)];
  y[idx] = v;
  yh[idx] = f2h_bits(v);
}

extern "C" void kernel_launch(void* const* d_in, const int* in_sizes, int n_in,
                              void* d_out, int out_size, void* d_ws, size_t ws_size,
                              hipStream_t stream) {
  const float* x = (const float*)d_in[0];
  const float* aug = (const float*)d_in[1];
  const float* W[5];
  const float* b[5];
  for (int i = 0; i < 5; ++i) {
    W[i] = (const float*)d_in[2 + 2 * i];
    b[i] = (const float*)d_in[3 + 2 * i];
  }

  char* ws = (char*)d_ws;
  auto alloc = [&](size_t bytes) -> char* {
    char* p = ws;
    ws += (bytes + 255) & ~(size_t)255;
    return p;
  };
  float* y = (float*)alloc((size_t)BATCH * 64 * 4);
  unsigned short* yh = (unsigned short*)alloc((size_t)BATCH * 64 * 2);
  unsigned short* h1 = (unsigned short*)alloc((size_t)BATCH * 1024 * 2);
  unsigned short* h2 = (unsigned short*)alloc((size_t)BATCH * 1024 * 2);
  float* ksum = (float*)alloc((size_t)BATCH * 64 * 4);
  const int Kdim[5] = {64, 1024, 1024, 1024, 1024};
  const int Ndim[5] = {1024, 1024, 1024, 1024, 64};
  unsigned short* Wh[5];
  for (int i = 0; i < 5; ++i)
    Wh[i] = (unsigned short*)alloc((size_t)Ndim[i] * Kdim[i] * 2);

  for (int i = 0; i < 5; ++i) {
    const int total = Ndim[i] * Kdim[i];
    conv_w<<<(total + 255) / 256, 256, 0, stream>>>(W[i], Wh[i], Ndim[i], Kdim[i]);
  }
  init_y<<<BATCH * 64 / 256, 256, 0, stream>>>(x, aug, y, yh);

  const float dt = 0.125f;
  float* outp = (float*)d_out;

  auto eval = [&](float t, int mode, float* op) {
    // layer 0: [B,64] x [64,1024]^T -> h1  (champion small-K kernel)
    gemm_h<256, 128, 4, 4, 64, 1024, true>
        <<<dim3(BATCH / 256, 1024 / 128), 512, 0, stream>>>(
            yh, Wh[0], W[0], b[0], t, h1);
    unsigned short* src = h1;
    unsigned short* dst = h2;
    for (int L = 1; L <= 3; ++L) {
      gemm_hb<256, 128, 4, 4, 1024, 1024, true>
          <<<dim3(BATCH / 256, 1024 / 128), 512, 0, stream>>>(
              src, Wh[L], W[L], b[L], t, dst);
      unsigned short* tmp = src; src = dst; dst = tmp;
    }
    gemm_l4<<<dim3(BATCH / 32, 1), 256, 0, stream>>>(
        src, Wh[4], W[4], b[4], t, y, ksum, yh, op, mode, dt);
  };

  for (int s = 0; s < 8; ++s) {
    const float t0 = s * dt;
    eval(t0, 0, nullptr);
    eval(t0 + 0.5f * dt, 1, nullptr);
    eval(t0 + 0.5f * dt, 2, nullptr);
    eval(t0 + dt, 3, (s == 7) ? outp : nullptr);
  }
}

// Round 5
// 4509.980 us; speedup vs baseline: 1.8464x; 1.8464x over previous
//
#include <hip/hip_runtime.h>
#include <cstdint>
#include <cstddef>

#define BATCH 16384

typedef float f32x4 __attribute__((ext_vector_type(4)));
typedef _Float16 f16x8 __attribute__((ext_vector_type(8)));

__device__ __forceinline__ unsigned short f2h_bits(float f) {
  _Float16 h = (_Float16)f;
  return __builtin_bit_cast(unsigned short, h);
}

__device__ __forceinline__ void async_cp16(const void* g, void* l) {
  __builtin_amdgcn_global_load_lds(
      (const __attribute__((address_space(1))) unsigned int*)g,
      (__attribute__((address_space(3))) unsigned int*)l, 16, 0, 0);
}

// Barrier WITHOUT the full vmcnt(0) drain __syncthreads would force.
#define PIPE_BAR_3() asm volatile("s_waitcnt vmcnt(3)\n\ts_barrier" ::: "memory")
#define PIPE_BAR_0() asm volatile("s_waitcnt vmcnt(0)\n\ts_barrier" ::: "memory")

// ---------------------------------------------------------------------------
// Hidden-layer GEMM: champion tile + doubled occupancy via 512-thr blocks.
// C = relu(A[M,K] * Bw[N,K]^T + (bias + t*W[:,K])).
// Block tile 256x128, 8 waves in 4x2, wave tile 64x64 (RT=CT=4, acc=64 VGPR),
// BK=32, 3-stage LDS pipeline: iter k waits s_waitcnt vmcnt(3) (stage k's 3
// loads done, stage k+1's 3 STAY IN FLIGHT through compute(k)), s_barrier,
// issues stage k+2. LDS 72.5 KB -> 2 blocks/CU x 8 waves = 4 waves/SIMD.
// VGPR budget for 4 waves/SIMD is 128; acc 64 + frags 32 fits.
// XOR swizzle cp = c ^ ((row>>1)&3): frag ds_read_b128 2-way max (free).
// Session R1-R4 post-mortem: 8-phase 256x256 lockstep (3 orderings) and
// B-from-global all measured SLOWER (43.8/55/83 us vs ~40); 2 desync'd
// blocks/CU beats 1-block/CU deep pipelines at these shapes; B must be LDS.
// ---------------------------------------------------------------------------
template <int BM, int BN, int RT, int CT, int K, int N, bool RELU>
__launch_bounds__(512, 4)
__global__ void gemm_h(const unsigned short* __restrict__ A,
                       const unsigned short* __restrict__ Bw,
                       const float* __restrict__ Wfull,
                       const float* __restrict__ bias,
                       float tval,
                       unsigned short* __restrict__ Ch) {
  constexpr int BK = 32;
  constexpr int NI = K / BK;
  static_assert(NI >= 2, "pipeline needs >=2 stages");
  static_assert((BM * 4 + BN * 4) / 512 == 3, "vmcnt(3) assumes 3 loads/stage");
  static_assert(BM == 4 * RT * 16 && BN == 2 * CT * 16, "4x2 waves");
  __shared__ __align__(16) unsigned short smA[3][BM * BK];
  __shared__ __align__(16) unsigned short smB[3][BN * BK];
  __shared__ float biasLds[BN];

  const int tid = threadIdx.x;
  const int wave = tid >> 6;
  const int lane = tid & 63;
  const int quad = lane >> 4;
  const int r16 = lane & 15;

  const int rowA0 = blockIdx.x * BM;
  const int rowB0 = blockIdx.y * BN;
  const int waveM = wave >> 1;  // 4 wave-rows
  const int waveN = wave & 1;   // 2 wave-cols

  // effective bias = b[col] + t * W[col][K] (time-column fold); its vmcnt
  // drain happens once, before the pipeline starts.
  if (tid < BN) {
    const int col = rowB0 + tid;
    biasLds[tid] = bias[col] + tval * Wfull[(size_t)col * (K + 1) + K];
  }

  auto stage = [&](int k0, int buf) {
#pragma unroll
    for (int i = 0; i < BM * 4 / 512; ++i) {  // A: 1024 chunks, 2/thread
      const int s = i * 512 + tid;                // LDS 16B-chunk position
      const int row = s >> 2;
      const int c = (s & 3) ^ ((row >> 1) & 3);   // global chunk (swizzled)
      const unsigned short* g = A + (size_t)(rowA0 + row) * K + (k0 + c * 8);
      char* l = ((char*)smA[buf]) + (size_t)(i * 512 + (wave << 6)) * 16;
      async_cp16(g, l);
    }
    {  // B: 512 chunks, 1/thread
      const int s = tid;
      const int row = s >> 2;
      const int c = (s & 3) ^ ((row >> 1) & 3);
      const unsigned short* g = Bw + (size_t)(rowB0 + row) * K + (k0 + c * 8);
      char* l = ((char*)smB[buf]) + (size_t)((wave << 6)) * 16;
      async_cp16(g, l);
    }
  };

  f32x4 acc[RT][CT];
  const f32x4 zero = {0.f, 0.f, 0.f, 0.f};
#pragma unroll
  for (int i = 0; i < RT; ++i)
#pragma unroll
    for (int j = 0; j < CT; ++j) acc[i][j] = zero;

  auto compute = [&](int buf) {
    const unsigned short* sA = smA[buf];
    const unsigned short* sB = smB[buf];
    f16x8 af[RT], bfr[CT];
#pragma unroll
    for (int nt = 0; nt < CT; ++nt) {
      const int row = waveN * (CT * 16) + nt * 16 + r16;
      const int cp = quad ^ ((row >> 1) & 3);
      bfr[nt] = *(const f16x8*)(sB + row * BK + cp * 8);
    }
#pragma unroll
    for (int mt = 0; mt < RT; ++mt) {
      const int row = waveM * (RT * 16) + mt * 16 + r16;
      const int cp = quad ^ ((row >> 1) & 3);
      af[mt] = *(const f16x8*)(sA + row * BK + cp * 8);
    }
#pragma unroll
    for (int mt = 0; mt < RT; ++mt)
#pragma unroll
      for (int nt = 0; nt < CT; ++nt)
        acc[mt][nt] =
            __builtin_amdgcn_mfma_f32_16x16x32_f16(af[mt], bfr[nt], acc[mt][nt], 0, 0, 0);
  };

  stage(0, 0);
  stage(BK, 1);

#pragma unroll
  for (int kk = 0; kk < NI - 1; ++kk) {
    PIPE_BAR_3();  // stage kk complete; stage kk+1 still in flight
    if (kk + 2 < NI) stage((kk + 2) * BK, (kk + 2) % 3);
    compute(kk % 3);
  }
  PIPE_BAR_0();  // tail: drain the final stage
  compute((NI - 1) % 3);

  // epilogue: C/D layout col=lane&15, row=(lane>>4)*4+r
#pragma unroll
  for (int mt = 0; mt < RT; ++mt) {
    const int grow0 = rowA0 + waveM * (RT * 16) + mt * 16 + quad * 4;
#pragma unroll
    for (int nt = 0; nt < CT; ++nt) {
      const int lcol = waveN * (CT * 16) + nt * 16 + r16;
      const int gcol = rowB0 + lcol;
      const float bi = biasLds[lcol];
#pragma unroll
      for (int r = 0; r < 4; ++r) {
        float v = acc[mt][nt][r] + bi;
        if (RELU) v = fmaxf(v, 0.0f);
        Ch[(size_t)(grow0 + r) * N + gcol] = f2h_bits(v);
      }
    }
  }
}

// ---------------------------------------------------------------------------
// Last layer fused with RK4 combine (BM=32, BN=64 full width), dbuf BK=32.
// ---------------------------------------------------------------------------
__launch_bounds__(256, 4)
__global__ void gemm_l4(const unsigned short* __restrict__ A,
                        const unsigned short* __restrict__ Bw,
                        const float* __restrict__ Wfull,
                        const float* __restrict__ bias,
                        float tval,
                        float* __restrict__ y, float* __restrict__ ksum,
                        unsigned short* __restrict__ yh,
                        float* __restrict__ outp, int mode, float dt) {
  constexpr int K = 1024, BK = 32, BM = 32, BN = 64, NI = K / BK;
  __shared__ __align__(16) unsigned short smA[2][BM * BK];
  __shared__ __align__(16) unsigned short smB[2][BN * BK];
  __shared__ float biasLds[BN];

  const int tid = threadIdx.x;
  const int wave = tid >> 6;
  const int lane = tid & 63;
  const int quad = lane >> 4;
  const int r16 = lane & 15;

  const int rowA0 = blockIdx.x * BM;
  const int waveM = wave >> 1;
  const int waveN = wave & 1;

  if (tid < BN) {
    biasLds[tid] = bias[tid] + tval * Wfull[(size_t)tid * (K + 1) + K];
  }

  auto stage = [&](int k0, int buf) {
    if (tid < BM * 4) {  // A: 128 chunks
      const int s = tid;
      const int row = s >> 2;
      const int c = (s & 3) ^ ((row >> 1) & 3);
      const unsigned short* g = A + (size_t)(rowA0 + row) * K + (k0 + c * 8);
      char* l = ((char*)smA[buf]) + (size_t)(wave << 6) * 16;
      async_cp16(g, l);
    }
    {  // B: 256 chunks
      const int s = tid;
      const int row = s >> 2;
      const int c = (s & 3) ^ ((row >> 1) & 3);
      const unsigned short* g = Bw + (size_t)row * K + (k0 + c * 8);
      char* l = ((char*)smB[buf]) + (size_t)(wave << 6) * 16;
      async_cp16(g, l);
    }
  };

  f32x4 acc[2];
  const f32x4 zero = {0.f, 0.f, 0.f, 0.f};
  acc[0] = zero; acc[1] = zero;

  stage(0, 0);

#pragma unroll 2
  for (int kk = 0; kk < NI; ++kk) {
    __syncthreads();
    if (kk + 1 < NI) stage((kk + 1) * BK, (kk + 1) & 1);

    const unsigned short* sA = smA[kk & 1];
    const unsigned short* sB = smB[kk & 1];
    f16x8 af, bfr[2];
    {
      const int row = waveM * 16 + r16;
      const int cp = quad ^ ((row >> 1) & 3);
      af = *(const f16x8*)(sA + row * BK + cp * 8);
    }
#pragma unroll
    for (int nt = 0; nt < 2; ++nt) {
      const int row = (waveN * 2 + nt) * 16 + r16;
      const int cp = quad ^ ((row >> 1) & 3);
      bfr[nt] = *(const f16x8*)(sB + row * BK + cp * 8);
    }
#pragma unroll
    for (int nt = 0; nt < 2; ++nt)
      acc[nt] = __builtin_amdgcn_mfma_f32_16x16x32_f16(af, bfr[nt], acc[nt], 0, 0, 0);
  }

  // epilogue + fused RK4 combine
  const int grow0 = rowA0 + waveM * 16 + quad * 4;
#pragma unroll
  for (int nt = 0; nt < 2; ++nt) {
    const int col = waveN * 32 + nt * 16 + r16;
    const float bi = biasLds[col];
#pragma unroll
    for (int r = 0; r < 4; ++r) {
      const float k = acc[nt][r] + bi;
      const int row = grow0 + r;
      const int idx = row * 64 + col;
      if (mode == 0) {
        ksum[idx] = k;
        yh[idx] = f2h_bits(y[idx] + 0.5f * dt * k);
      } else if (mode == 1) {
        ksum[idx] += 2.f * k;
        yh[idx] = f2h_bits(y[idx] + 0.5f * dt * k);
      } else if (mode == 2) {
        ksum[idx] += 2.f * k;
        yh[idx] = f2h_bits(y[idx] + dt * k);
      } else {
        const float yn = y[idx] + (dt / 6.f) * (ksum[idx] + k);
        y[idx] = yn;
        yh[idx] = f2h_bits(yn);
        if (outp && col < 32) outp[row * 32 + col] = yn;
      }
    }
  }
}

// fp32 W (N x (K+1), time col dropped) -> fp16 Wh (N x K), row-major
__global__ void conv_w(const float* __restrict__ W, unsigned short* __restrict__ Wh,
                       int N, int K) {
  const int idx = blockIdx.x * 256 + threadIdx.x;
  if (idx < N * K) {
    const int n = idx / K;
    const int k = idx - n * K;
    Wh[idx] = f2h_bits(W[(size_t)n * (K + 1) + k]);
  }
}

// y0 = concat(x, aug); row-major fp32 + fp16 copy
__global__ void init_y(const float* __restrict__ x, const float* __restrict__ aug,
                       float* __restrict__ y, unsigned short* __restrict__ yh) {
  const int idx = blockIdx.x * 256 + threadIdx.x;  // BATCH*64
  const int i = idx >> 6;
  const int j = idx & 63;
  const float v = (j < 32) ? x[i * 32 + j] : aug[i * 32 + (j - 32)];
  y[idx] = v;
  yh[idx] = f2h_bits(v);
}

extern "C" void kernel_launch(void* const* d_in, const int* in_sizes, int n_in,
                              void* d_out, int out_size, void* d_ws, size_t ws_size,
                              hipStream_t stream) {
  const float* x = (const float*)d_in[0];
  const float* aug = (const float*)d_in[1];
  const float* W[5];
  const float* b[5];
  for (int i = 0; i < 5; ++i) {
    W[i] = (const float*)d_in[2 + 2 * i];
    b[i] = (const float*)d_in[3 + 2 * i];
  }

  char* ws = (char*)d_ws;
  auto alloc = [&](size_t bytes) -> char* {
    char* p = ws;
    ws += (bytes + 255) & ~(size_t)255;
    return p;
  };
  float* y = (float*)alloc((size_t)BATCH * 64 * 4);
  unsigned short* yh = (unsigned short*)alloc((size_t)BATCH * 64 * 2);
  unsigned short* h1 = (unsigned short*)alloc((size_t)BATCH * 1024 * 2);
  unsigned short* h2 = (unsigned short*)alloc((size_t)BATCH * 1024 * 2);
  float* ksum = (float*)alloc((size_t)BATCH * 64 * 4);
  const int Kdim[5] = {64, 1024, 1024, 1024, 1024};
  const int Ndim[5] = {1024, 1024, 1024, 1024, 64};
  unsigned short* Wh[5];
  for (int i = 0; i < 5; ++i)
    Wh[i] = (unsigned short*)alloc((size_t)Ndim[i] * Kdim[i] * 2);

  for (int i = 0; i < 5; ++i) {
    const int total = Ndim[i] * Kdim[i];
    conv_w<<<(total + 255) / 256, 256, 0, stream>>>(W[i], Wh[i], Ndim[i], Kdim[i]);
  }
  init_y<<<BATCH * 64 / 256, 256, 0, stream>>>(x, aug, y, yh);

  const float dt = 0.125f;
  float* outp = (float*)d_out;

  auto eval = [&](float t, int mode, float* op) {
    // layer 0: [B,64] x [64,1024]^T -> h1
    gemm_h<256, 128, 4, 4, 64, 1024, true>
        <<<dim3(BATCH / 256, 1024 / 128), 512, 0, stream>>>(
            yh, Wh[0], W[0], b[0], t, h1);
    unsigned short* src = h1;
    unsigned short* dst = h2;
    for (int L = 1; L <= 3; ++L) {
      gemm_h<256, 128, 4, 4, 1024, 1024, true>
          <<<dim3(BATCH / 256, 1024 / 128), 512, 0, stream>>>(
              src, Wh[L], W[L], b[L], t, dst);
      unsigned short* tmp = src; src = dst; dst = tmp;
    }
    gemm_l4<<<dim3(BATCH / 32, 1), 256, 0, stream>>>(
        src, Wh[4], W[4], b[4], t, y, ksum, yh, op, mode, dt);
  };

  for (int s = 0; s < 8; ++s) {
    const float t0 = s * dt;
    eval(t0, 0, nullptr);
    eval(t0 + 0.5f * dt, 1, nullptr);
    eval(t0 + 0.5f * dt, 2, nullptr);
    eval(t0 + dt, 3, (s == 7) ? outp : nullptr);
  }
}